// Round 11
// baseline (703.324 us; speedup 1.0000x reference)
//
#include <hip/hip_runtime.h>

#define N_MET 100000
#define N_RXN 50000
#define E_SUB 2000000
#define E_ALL 4000000
#define MSG_DIM 16
#define HIDDEN 32

// dxdt-side binning: buckets of 256 metabolites, fixed 4096-edge tiles.
#define NBKT_A 391            // ceil(100000/256)
#define NB_ALL 977            // ceil(4000000/4096)
// v-side binning: buckets of 64 reactions, fixed 4096-edge tiles.
#define NBKT_S 782            // ceil(50000/64)
#define NB_SUB 489            // ceil(2000000/4096)

// HW model (R1-R10): scattered GLOBAL atomics are serviced memory-side at
// ~19-20 G ops/s regardless of scope/replication/footprint (R2 replication,
// R3 line-grouping, R9 workgroup-scope all failed to move it). LDS atomics
// are not subject to that wall. This pipeline has ZERO global atomics.

// ---- generic scans -----------------------------------------------------------

// per-bucket exclusive scan over blocks: hist[bk][b] -> within-bucket offsets
// (in place); tot[b] = bucket total. One block per bucket (grid = nbkt).
__global__ __launch_bounds__(256) void scan_cols_kernel(
    int* __restrict__ hist, int* __restrict__ tot, int nblocks, int nbkt)
{
    __shared__ int wsum[4];
    const int b = blockIdx.x;
    const int t = threadIdx.x, lane = t & 63, w = t >> 6;
    int carry = 0;
    for (int basei = 0; basei < nblocks; basei += 256) {
        const int bk = basei + t;
        const int val = (bk < nblocks) ? hist[(size_t)bk * nbkt + b] : 0;
        int x = val;
#pragma unroll
        for (int off = 1; off < 64; off <<= 1) {
            const int y = __shfl_up(x, off);
            if (lane >= off) x += y;
        }
        if (lane == 63) wsum[w] = x;
        __syncthreads();
        if (w == 0) {
            int s = (lane < 4) ? wsum[lane] : 0;
#pragma unroll
            for (int off = 1; off < 4; off <<= 1) {
                const int y = __shfl_up(s, off);
                if (lane >= off) s += y;
            }
            if (lane < 4) wsum[lane] = s;
        }
        __syncthreads();
        const int excl = carry + ((w > 0) ? wsum[w - 1] : 0) + x - val;
        if (bk < nblocks) hist[(size_t)bk * nbkt + b] = excl;
        carry += wsum[3];
        __syncthreads();
    }
    if (t == 0) tot[b] = carry;
}

// exclusive scan of tot[nbkt] -> base[nbkt]. Single block.
__global__ __launch_bounds__(256) void scan_base_kernel(
    const int* __restrict__ tot, int* __restrict__ base, int nbkt)
{
    __shared__ int wsum[4];
    const int t = threadIdx.x, lane = t & 63, w = t >> 6;
    int carry = 0;
    for (int basei = 0; basei < nbkt; basei += 256) {
        const int i = basei + t;
        const int val = (i < nbkt) ? tot[i] : 0;
        int x = val;
#pragma unroll
        for (int off = 1; off < 64; off <<= 1) {
            const int y = __shfl_up(x, off);
            if (lane >= off) x += y;
        }
        if (lane == 63) wsum[w] = x;
        __syncthreads();
        if (w == 0) {
            int s = (lane < 4) ? wsum[lane] : 0;
#pragma unroll
            for (int off = 1; off < 4; off <<= 1) {
                const int y = __shfl_up(s, off);
                if (lane >= off) s += y;
            }
            if (lane < 4) wsum[lane] = s;
        }
        __syncthreads();
        const int excl = carry + ((w > 0) ? wsum[w - 1] : 0) + x - val;
        if (i < nbkt) base[i] = excl;
        carry += wsum[3];
        __syncthreads();
    }
}

// ---- Phase 1: v via reaction-bucket binning ---------------------------------

// 1a. per-block LDS histogram of rxn_sub>>6 over a fixed 4096-edge tile.
__global__ __launch_bounds__(256) void hist_sub_kernel(
    const int* __restrict__ rxn_sub, int* __restrict__ hist)
{
    __shared__ int hb[NBKT_S];
    const int t = threadIdx.x, bk = blockIdx.x;
    for (int i = t; i < NBKT_S; i += 256) hb[i] = 0;
    __syncthreads();
#pragma unroll
    for (int it = 0; it < 4; ++it) {
        const int i = bk * 1024 + it * 256 + t;
        if (i < E_SUB / 4) {
            const int4 r = ((const int4*)rxn_sub)[i];
            atomicAdd(&hb[r.x >> 6], 1);
            atomicAdd(&hb[r.y >> 6], 1);
            atomicAdd(&hb[r.z >> 6], 1);
            atomicAdd(&hb[r.w >> 6], 1);
        }
    }
    __syncthreads();
    for (int i = t; i < NBKT_S; i += 256) hist[bk * NBKT_S + i] = hb[i];
}

// 1b. scatter: LDS-atomic rank into per-(block,bucket) runs; payload
// {x_met[met], sto} + rxn&63. Zero global atomics.
__global__ __launch_bounds__(256) void scatter_bin_sub_kernel(
    const float* __restrict__ x_met, const float* __restrict__ sto_sub,
    const int* __restrict__ met_sub, const int* __restrict__ rxn_sub,
    const int* __restrict__ hist, const int* __restrict__ base,
    float2* __restrict__ pxs, unsigned char* __restrict__ pr)
{
    __shared__ int offs[NBKT_S];
    const int t = threadIdx.x, bk = blockIdx.x;
    for (int i = t; i < NBKT_S; i += 256)
        offs[i] = hist[bk * NBKT_S + i] + base[i];
    __syncthreads();
#pragma unroll
    for (int it = 0; it < 16; ++it) {
        const int e = bk * 4096 + it * 256 + t;
        if (e < E_SUB) {
            const int r = rxn_sub[e];
            const float x = x_met[met_sub[e]];
            const float s = sto_sub[e];
            const int idx = atomicAdd(&offs[r >> 6], 1);
            pxs[idx] = make_float2(x, s);
            pr[idx] = (unsigned char)(r & 63);
        }
    }
}

// 1c. one block per bucket of 64 reactions: coalesced read of the bucket's
// contiguous edge segment; per-edge msg MLP in registers (2->32tanh->16);
// LDS-atomic accumulate into h[64][17]; then rate MLP + softplus -> v.
// NOTE: j-loop is "#pragma unroll 2" — full unroll hoists ~512 LDS weight
// loads, natural pressure ~256 VGPR, and any cap <=128 spills msg[16] to
// scratch (rounds 5/6: GBs of HBM spill traffic). d-loop stays fully unrolled.
__global__ __launch_bounds__(256, 2) void bucket_msg_kernel(
    const float2* __restrict__ pxs, const unsigned char* __restrict__ pr,
    const int* __restrict__ base, const int* __restrict__ tot,
    const float* __restrict__ W1m, const float* __restrict__ b1m,
    const float* __restrict__ W2m, const float* __restrict__ b2m,
    const float* __restrict__ W1r, const float* __restrict__ b1r,
    const float* __restrict__ W2r, const float* __restrict__ b2r,
    float* __restrict__ v)
{
    __shared__ float sW1m[2 * HIDDEN];
    __shared__ float sb1m[HIDDEN];
    __shared__ float sW2m[HIDDEN * MSG_DIM];
    __shared__ float sb2m[MSG_DIM];
    __shared__ float sW1r[MSG_DIM * HIDDEN];
    __shared__ float sb1r[HIDDEN];
    __shared__ float sW2r[HIDDEN];
    __shared__ float sb2r;
    __shared__ float sh[64 * 17];     // h[64 rxns][16+1 pad]
    __shared__ int   scnt[64];
    const int t = threadIdx.x;
    if (t < 2 * HIDDEN) sW1m[t] = W1m[t];
    if (t < HIDDEN)     sb1m[t] = b1m[t];
    for (int i = t; i < HIDDEN * MSG_DIM; i += 256) sW2m[i] = W2m[i];
    if (t < MSG_DIM)    sb2m[t] = b2m[t];
    for (int i = t; i < MSG_DIM * HIDDEN; i += 256) sW1r[i] = W1r[i];
    if (t >= 64 && t < 64 + HIDDEN) { sb1r[t - 64] = b1r[t - 64]; sW2r[t - 64] = W2r[t - 64]; }
    if (t == 128) sb2r = b2r[0];
    for (int i = t; i < 64 * 17; i += 256) sh[i] = 0.0f;
    if (t < 64) scnt[t] = 0;
    __syncthreads();

    const int b = blockIdx.x;
    const int beg = base[b];
    const int end = beg + tot[b];

    for (int i = beg + t; i < end; i += 256) {
        const float2 xs = pxs[i];
        const int rl = (int)pr[i];
        float msg[MSG_DIM];
#pragma unroll
        for (int d = 0; d < MSG_DIM; ++d) msg[d] = 0.0f;
#pragma unroll 2
        for (int j = 0; j < HIDDEN; ++j) {
            const float hj =
                tanhf(fmaf(xs.x, sW1m[j], fmaf(xs.y, sW1m[HIDDEN + j], sb1m[j])));
#pragma unroll
            for (int d = 0; d < MSG_DIM; ++d)
                msg[d] = fmaf(hj, sW2m[j * MSG_DIM + d], msg[d]);
        }
#pragma unroll
        for (int d = 0; d < MSG_DIM; ++d)
            atomicAdd(&sh[rl * 17 + d], msg[d]);
        atomicAdd(&scnt[rl], 1);
    }
    __syncthreads();

    // rate MLP: thread t (<64) owns reaction b*64+t
    if (t < 64) {
        const int r = b * 64 + t;
        if (r < N_RXN) {
            const float cnt = (float)scnt[t];
            float h[MSG_DIM];
#pragma unroll
            for (int d = 0; d < MSG_DIM; ++d)
                h[d] = fmaf(cnt, sb2m[d], sh[t * 17 + d]);
            float acc = sb2r;
#pragma unroll 2
            for (int j = 0; j < HIDDEN; ++j) {
                float z = sb1r[j];
#pragma unroll
                for (int d = 0; d < MSG_DIM; ++d)
                    z = fmaf(h[d], sW1r[d * HIDDEN + j], z);
                acc = fmaf(tanhf(z), sW2r[j], acc);
            }
            v[r] = fmaxf(acc, 0.0f) + log1pf(expf(-fabsf(acc)));
        }
    }
}

// ---- Phase 2: dxdt via metabolite-bucket binning (unchanged from R10) -------

__global__ __launch_bounds__(256) void hist_all_kernel(
    const int* __restrict__ met_all, int* __restrict__ hist)
{
    __shared__ int hb[NBKT_A];
    const int t = threadIdx.x, bk = blockIdx.x;
    for (int i = t; i < NBKT_A; i += 256) hb[i] = 0;
    __syncthreads();
#pragma unroll
    for (int it = 0; it < 4; ++it) {
        const int i = bk * 1024 + it * 256 + t;
        if (i < E_ALL / 4) {
            const int4 m = ((const int4*)met_all)[i];
            atomicAdd(&hb[m.x >> 8], 1);
            atomicAdd(&hb[m.y >> 8], 1);
            atomicAdd(&hb[m.z >> 8], 1);
            atomicAdd(&hb[m.w >> 8], 1);
        }
    }
    __syncthreads();
    for (int i = t; i < NBKT_A; i += 256) hist[bk * NBKT_A + i] = hb[i];
}

__global__ __launch_bounds__(256) void scatter_bin_kernel(
    const float* __restrict__ sto_all, const float* __restrict__ v,
    const int* __restrict__ met_all, const int* __restrict__ rxn_all,
    const int* __restrict__ hist, const int* __restrict__ base,
    float* __restrict__ pc, unsigned char* __restrict__ pm)
{
    __shared__ int offs[NBKT_A];
    const int t = threadIdx.x, bk = blockIdx.x;
    for (int i = t; i < NBKT_A; i += 256)
        offs[i] = hist[bk * NBKT_A + i] + base[i];
    __syncthreads();
#pragma unroll
    for (int it = 0; it < 16; ++it) {
        const int e = bk * 4096 + it * 256 + t;
        if (e < E_ALL) {
            const int m = met_all[e];
            const float c = sto_all[e] * v[rxn_all[e]];
            const int idx = atomicAdd(&offs[m >> 8], 1);
            pc[idx] = c;
            pm[idx] = (unsigned char)(m & 255);
        }
    }
}

__global__ __launch_bounds__(256) void bucket_accum_kernel(
    const float* __restrict__ pc, const unsigned char* __restrict__ pm,
    const int* __restrict__ base, const int* __restrict__ tot,
    float* __restrict__ dxdt)
{
    __shared__ float acc[256];
    const int b = blockIdx.x, t = threadIdx.x;
    acc[t] = 0.0f;
    __syncthreads();
    const int beg = base[b];
    const int end = beg + tot[b];
    for (int i = beg + t; i < end; i += 256)
        atomicAdd(&acc[pm[i]], pc[i]);
    __syncthreads();
    const int met = b * 256 + t;
    if (met < N_MET) dxdt[met] = acc[t];
}

extern "C" void kernel_launch(void* const* d_in, const int* in_sizes, int n_in,
                              void* d_out, int out_size, void* d_ws, size_t ws_size,
                              hipStream_t stream) {
    const float* x_met   = (const float*)d_in[0];
    const float* sto_sub = (const float*)d_in[1];
    const float* sto_all = (const float*)d_in[2];
    const float* W1m     = (const float*)d_in[3];
    const float* b1m     = (const float*)d_in[4];
    const float* W2m     = (const float*)d_in[5];
    const float* b2m     = (const float*)d_in[6];
    const float* W1r     = (const float*)d_in[7];
    const float* b1r     = (const float*)d_in[8];
    const float* W2r     = (const float*)d_in[9];
    const float* b2r     = (const float*)d_in[10];
    const int*   met_sub = (const int*)d_in[11];
    const int*   rxn_sub = (const int*)d_in[12];
    const int*   met_all = (const int*)d_in[13];
    const int*   rxn_all = (const int*)d_in[14];

    float* dxdt = (float*)d_out;             // [N_MET]
    float* v    = dxdt + N_MET;              // [N_RXN]

    // workspace layout. histA is SHARED by both phases (phase-1 hist dead
    // after scatter_bin_sub; hist_all rewrites it). Payload region shared:
    // pxs/pr (18 MB, dead after bucket_msg) alias pc/pm (20 MB, written
    // strictly later in stream order). No memsets needed anywhere.
    const size_t HIST_ELEMS =
        ((size_t)NB_SUB * NBKT_S > (size_t)NB_ALL * NBKT_A)
            ? (size_t)NB_SUB * NBKT_S : (size_t)NB_ALL * NBKT_A;
    char* ws = (char*)d_ws;
    int* histA  = (int*)ws;  ws += ((HIST_ELEMS * 4 + 15) / 16) * 16;
    int* tot_s  = (int*)ws;  ws += ((sizeof(int) * NBKT_S + 15) / 16) * 16;
    int* base_s = (int*)ws;  ws += ((sizeof(int) * NBKT_S + 15) / 16) * 16;
    int* tot_a  = (int*)ws;  ws += ((sizeof(int) * NBKT_A + 15) / 16) * 16;
    int* base_a = (int*)ws;  ws += ((sizeof(int) * NBKT_A + 15) / 16) * 16;
    char* P = ws;                                     // payload union, 20 MB
    float2*        pxs = (float2*)P;                  // [E_SUB]  16 MB
    unsigned char* pr  = (unsigned char*)(P + (size_t)E_SUB * 8);  // 2 MB
    float*         pc  = (float*)P;                   // [E_ALL]  16 MB
    unsigned char* pm  = (unsigned char*)(P + (size_t)E_ALL * 4);  // 4 MB

    // phase 1: v
    hist_sub_kernel<<<NB_SUB, 256, 0, stream>>>(rxn_sub, histA);
    scan_cols_kernel<<<NBKT_S, 256, 0, stream>>>(histA, tot_s, NB_SUB, NBKT_S);
    scan_base_kernel<<<1, 256, 0, stream>>>(tot_s, base_s, NBKT_S);
    scatter_bin_sub_kernel<<<NB_SUB, 256, 0, stream>>>(
        x_met, sto_sub, met_sub, rxn_sub, histA, base_s, pxs, pr);
    bucket_msg_kernel<<<NBKT_S, 256, 0, stream>>>(
        pxs, pr, base_s, tot_s, W1m, b1m, W2m, b2m, W1r, b1r, W2r, b2r, v);

    // phase 2: dxdt
    hist_all_kernel<<<NB_ALL, 256, 0, stream>>>(met_all, histA);
    scan_cols_kernel<<<NBKT_A, 256, 0, stream>>>(histA, tot_a, NB_ALL, NBKT_A);
    scan_base_kernel<<<1, 256, 0, stream>>>(tot_a, base_a, NBKT_A);
    scatter_bin_kernel<<<NB_ALL, 256, 0, stream>>>(
        sto_all, v, met_all, rxn_all, histA, base_a, pc, pm);
    bucket_accum_kernel<<<NBKT_A, 256, 0, stream>>>(pc, pm, base_a, tot_a, dxdt);
}

// Round 12
// 565.571 us; speedup vs baseline: 1.2436x; 1.2436x over previous
//
#include <hip/hip_runtime.h>

#define N_MET 100000
#define N_RXN 50000
#define E_SUB 2000000
#define E_ALL 4000000
#define MSG_DIM 16
#define HIDDEN 32

// dxdt-side binning: buckets of 256 metabolites, fixed 4096-edge tiles.
#define NBKT_A 391            // ceil(100000/256)
#define NB_ALL 977            // ceil(4000000/4096)
// v-side binning: buckets of 64 reactions, fixed 4096-edge tiles.
#define NBKT_S 782            // ceil(50000/64)
#define NB_SUB 489            // ceil(2000000/4096)

// HW model (R1-R11): scattered GLOBAL atomics are serviced memory-side at
// ~19-20 G ops/s regardless of scope/replication/footprint. LDS atomics are
// exempt. R11 lesson: binning kernels with <16 waves/CU are latency-starved
// (bucket_msg 318us @ VALUBusy 21%) — launch 1024-thread blocks so ~2 blocks/CU
// = 32 waves/CU. Payloads carry their sub-bucket index in low mantissa bits
// (rel err <= 3e-5, output threshold 0.56 — negligible).

// ---- generic scans -----------------------------------------------------------

__global__ __launch_bounds__(256) void scan_cols_kernel(
    int* __restrict__ hist, int* __restrict__ tot, int nblocks, int nbkt)
{
    __shared__ int wsum[4];
    const int b = blockIdx.x;
    const int t = threadIdx.x, lane = t & 63, w = t >> 6;
    int carry = 0;
    for (int basei = 0; basei < nblocks; basei += 256) {
        const int bk = basei + t;
        const int val = (bk < nblocks) ? hist[(size_t)bk * nbkt + b] : 0;
        int x = val;
#pragma unroll
        for (int off = 1; off < 64; off <<= 1) {
            const int y = __shfl_up(x, off);
            if (lane >= off) x += y;
        }
        if (lane == 63) wsum[w] = x;
        __syncthreads();
        if (w == 0) {
            int s = (lane < 4) ? wsum[lane] : 0;
#pragma unroll
            for (int off = 1; off < 4; off <<= 1) {
                const int y = __shfl_up(s, off);
                if (lane >= off) s += y;
            }
            if (lane < 4) wsum[lane] = s;
        }
        __syncthreads();
        const int excl = carry + ((w > 0) ? wsum[w - 1] : 0) + x - val;
        if (bk < nblocks) hist[(size_t)bk * nbkt + b] = excl;
        carry += wsum[3];
        __syncthreads();
    }
    if (t == 0) tot[b] = carry;
}

__global__ __launch_bounds__(256) void scan_base_kernel(
    const int* __restrict__ tot, int* __restrict__ base, int nbkt)
{
    __shared__ int wsum[4];
    const int t = threadIdx.x, lane = t & 63, w = t >> 6;
    int carry = 0;
    for (int basei = 0; basei < nbkt; basei += 256) {
        const int i = basei + t;
        const int val = (i < nbkt) ? tot[i] : 0;
        int x = val;
#pragma unroll
        for (int off = 1; off < 64; off <<= 1) {
            const int y = __shfl_up(x, off);
            if (lane >= off) x += y;
        }
        if (lane == 63) wsum[w] = x;
        __syncthreads();
        if (w == 0) {
            int s = (lane < 4) ? wsum[lane] : 0;
#pragma unroll
            for (int off = 1; off < 4; off <<= 1) {
                const int y = __shfl_up(s, off);
                if (lane >= off) s += y;
            }
            if (lane < 4) wsum[lane] = s;
        }
        __syncthreads();
        const int excl = carry + ((w > 0) ? wsum[w - 1] : 0) + x - val;
        if (i < nbkt) base[i] = excl;
        carry += wsum[3];
        __syncthreads();
    }
}

// ---- Phase 1: v via reaction-bucket binning ---------------------------------

// 1a. per-block LDS histogram of rxn_sub>>6; one int4 per thread covers the
// whole 4096-edge tile.
__global__ __launch_bounds__(1024) void hist_sub_kernel(
    const int* __restrict__ rxn_sub, int* __restrict__ hist)
{
    __shared__ int hb[NBKT_S];
    const int t = threadIdx.x, bk = blockIdx.x;
    for (int i = t; i < NBKT_S; i += 1024) hb[i] = 0;
    __syncthreads();
    const int i = bk * 1024 + t;
    if (i < E_SUB / 4) {
        const int4 r = ((const int4*)rxn_sub)[i];
        atomicAdd(&hb[r.x >> 6], 1);
        atomicAdd(&hb[r.y >> 6], 1);
        atomicAdd(&hb[r.z >> 6], 1);
        atomicAdd(&hb[r.w >> 6], 1);
    }
    __syncthreads();
    for (int i2 = t; i2 < NBKT_S; i2 += 1024) hist[bk * NBKT_S + i2] = hb[i2];
}

// 1b. scatter: LDS-atomic rank into per-(block,bucket) runs; single float2
// payload {x, s'} where s' carries rxn&63 in its low 6 mantissa bits.
__global__ __launch_bounds__(1024) void scatter_bin_sub_kernel(
    const float* __restrict__ x_met, const float* __restrict__ sto_sub,
    const int* __restrict__ met_sub, const int* __restrict__ rxn_sub,
    const int* __restrict__ hist, const int* __restrict__ base,
    float2* __restrict__ pxs)
{
    __shared__ int offs[NBKT_S];
    const int t = threadIdx.x, bk = blockIdx.x;
    for (int i = t; i < NBKT_S; i += 1024)
        offs[i] = hist[bk * NBKT_S + i] + base[i];
    __syncthreads();
#pragma unroll
    for (int it = 0; it < 4; ++it) {
        const int e = bk * 4096 + it * 1024 + t;
        if (e < E_SUB) {
            const int r = rxn_sub[e];
            const float x = x_met[met_sub[e]];
            const int sb = (__float_as_int(sto_sub[e]) & ~63) | (r & 63);
            const int idx = atomicAdd(&offs[r >> 6], 1);
            pxs[idx] = make_float2(x, __int_as_float(sb));
        }
    }
}

// 1c. one block (1024 thr) per bucket of 64 reactions: coalesced segment read,
// per-edge msg MLP in registers, LDS-atomic accumulate into h[64][17], then
// rate MLP + softplus -> v.
// NOTE: j-loop "#pragma unroll 2" — full unroll inflates natural pressure to
// ~256 VGPR and any cap spills msg[16] (R5/R6: GBs of spill traffic). d-loop
// stays fully unrolled. Body measured 24 VGPR, so the (1024,8) 64-VGPR cap
// is safe and gives 2 blocks/CU = 32 waves/CU.
__global__ __launch_bounds__(1024, 8) void bucket_msg_kernel(
    const float2* __restrict__ pxs,
    const int* __restrict__ base, const int* __restrict__ tot,
    const float* __restrict__ W1m, const float* __restrict__ b1m,
    const float* __restrict__ W2m, const float* __restrict__ b2m,
    const float* __restrict__ W1r, const float* __restrict__ b1r,
    const float* __restrict__ W2r, const float* __restrict__ b2r,
    float* __restrict__ v)
{
    __shared__ float sW1m[2 * HIDDEN];
    __shared__ float sb1m[HIDDEN];
    __shared__ float sW2m[HIDDEN * MSG_DIM];
    __shared__ float sb2m[MSG_DIM];
    __shared__ float sW1r[MSG_DIM * HIDDEN];
    __shared__ float sb1r[HIDDEN];
    __shared__ float sW2r[HIDDEN];
    __shared__ float sb2r;
    __shared__ float sh[64 * 17];     // h[64 rxns][16+1 pad]
    __shared__ int   scnt[64];
    const int t = threadIdx.x;
    if (t < 2 * HIDDEN) sW1m[t] = W1m[t];
    if (t < HIDDEN)     sb1m[t] = b1m[t];
    if (t < HIDDEN * MSG_DIM) sW2m[t] = W2m[t];
    if (t < MSG_DIM)    sb2m[t] = b2m[t];
    if (t < MSG_DIM * HIDDEN) sW1r[t] = W1r[t];
    if (t >= 64 && t < 64 + HIDDEN) { sb1r[t - 64] = b1r[t - 64]; sW2r[t - 64] = W2r[t - 64]; }
    if (t == 128) sb2r = b2r[0];
    for (int i = t; i < 64 * 17; i += 1024) sh[i] = 0.0f;
    if (t < 64) scnt[t] = 0;
    __syncthreads();

    const int b = blockIdx.x;
    const int beg = base[b];
    const int end = beg + tot[b];

    for (int i = beg + t; i < end; i += 1024) {
        const float2 xs = pxs[i];
        const int rl = __float_as_int(xs.y) & 63;
        float msg[MSG_DIM];
#pragma unroll
        for (int d = 0; d < MSG_DIM; ++d) msg[d] = 0.0f;
#pragma unroll 2
        for (int j = 0; j < HIDDEN; ++j) {
            const float hj =
                tanhf(fmaf(xs.x, sW1m[j], fmaf(xs.y, sW1m[HIDDEN + j], sb1m[j])));
#pragma unroll
            for (int d = 0; d < MSG_DIM; ++d)
                msg[d] = fmaf(hj, sW2m[j * MSG_DIM + d], msg[d]);
        }
#pragma unroll
        for (int d = 0; d < MSG_DIM; ++d)
            atomicAdd(&sh[rl * 17 + d], msg[d]);
        atomicAdd(&scnt[rl], 1);
    }
    __syncthreads();

    // rate MLP: thread t (<64) owns reaction b*64+t
    if (t < 64) {
        const int r = b * 64 + t;
        if (r < N_RXN) {
            const float cnt = (float)scnt[t];
            float h[MSG_DIM];
#pragma unroll
            for (int d = 0; d < MSG_DIM; ++d)
                h[d] = fmaf(cnt, sb2m[d], sh[t * 17 + d]);
            float acc = sb2r;
#pragma unroll 2
            for (int j = 0; j < HIDDEN; ++j) {
                float z = sb1r[j];
#pragma unroll
                for (int d = 0; d < MSG_DIM; ++d)
                    z = fmaf(h[d], sW1r[d * HIDDEN + j], z);
                acc = fmaf(tanhf(z), sW2r[j], acc);
            }
            v[r] = fmaxf(acc, 0.0f) + log1pf(expf(-fabsf(acc)));
        }
    }
}

// ---- Phase 2: dxdt via metabolite-bucket binning ----------------------------

__global__ __launch_bounds__(1024) void hist_all_kernel(
    const int* __restrict__ met_all, int* __restrict__ hist)
{
    __shared__ int hb[NBKT_A];
    const int t = threadIdx.x, bk = blockIdx.x;
    for (int i = t; i < NBKT_A; i += 1024) hb[i] = 0;
    __syncthreads();
    const int i = bk * 1024 + t;
    if (i < E_ALL / 4) {
        const int4 m = ((const int4*)met_all)[i];
        atomicAdd(&hb[m.x >> 8], 1);
        atomicAdd(&hb[m.y >> 8], 1);
        atomicAdd(&hb[m.z >> 8], 1);
        atomicAdd(&hb[m.w >> 8], 1);
    }
    __syncthreads();
    for (int i2 = t; i2 < NBKT_A; i2 += 1024) hist[bk * NBKT_A + i2] = hb[i2];
}

// scatter: single 4B payload — contribution c with met&255 packed into its
// low 8 mantissa bits (rel err ~3e-5; threshold 0.56).
__global__ __launch_bounds__(1024) void scatter_bin_kernel(
    const float* __restrict__ sto_all, const float* __restrict__ v,
    const int* __restrict__ met_all, const int* __restrict__ rxn_all,
    const int* __restrict__ hist, const int* __restrict__ base,
    float* __restrict__ pc)
{
    __shared__ int offs[NBKT_A];
    const int t = threadIdx.x, bk = blockIdx.x;
    for (int i = t; i < NBKT_A; i += 1024)
        offs[i] = hist[bk * NBKT_A + i] + base[i];
    __syncthreads();
#pragma unroll
    for (int it = 0; it < 4; ++it) {
        const int e = bk * 4096 + it * 1024 + t;
        if (e < E_ALL) {
            const int m = met_all[e];
            const float c = sto_all[e] * v[rxn_all[e]];
            const int cb = (__float_as_int(c) & ~255) | (m & 255);
            const int idx = atomicAdd(&offs[m >> 8], 1);
            pc[idx] = __int_as_float(cb);
        }
    }
}

__global__ __launch_bounds__(1024) void bucket_accum_kernel(
    const float* __restrict__ pc,
    const int* __restrict__ base, const int* __restrict__ tot,
    float* __restrict__ dxdt)
{
    __shared__ float acc[256];
    const int b = blockIdx.x, t = threadIdx.x;
    if (t < 256) acc[t] = 0.0f;
    __syncthreads();
    const int beg = base[b];
    const int end = beg + tot[b];
    for (int i = beg + t; i < end; i += 1024) {
        const float pv = pc[i];
        atomicAdd(&acc[__float_as_int(pv) & 255], pv);
    }
    __syncthreads();
    if (t < 256) {
        const int met = b * 256 + t;
        if (met < N_MET) dxdt[met] = acc[t];
    }
}

extern "C" void kernel_launch(void* const* d_in, const int* in_sizes, int n_in,
                              void* d_out, int out_size, void* d_ws, size_t ws_size,
                              hipStream_t stream) {
    const float* x_met   = (const float*)d_in[0];
    const float* sto_sub = (const float*)d_in[1];
    const float* sto_all = (const float*)d_in[2];
    const float* W1m     = (const float*)d_in[3];
    const float* b1m     = (const float*)d_in[4];
    const float* W2m     = (const float*)d_in[5];
    const float* b2m     = (const float*)d_in[6];
    const float* W1r     = (const float*)d_in[7];
    const float* b1r     = (const float*)d_in[8];
    const float* W2r     = (const float*)d_in[9];
    const float* b2r     = (const float*)d_in[10];
    const int*   met_sub = (const int*)d_in[11];
    const int*   rxn_sub = (const int*)d_in[12];
    const int*   met_all = (const int*)d_in[13];
    const int*   rxn_all = (const int*)d_in[14];

    float* dxdt = (float*)d_out;             // [N_MET]
    float* v    = dxdt + N_MET;              // [N_RXN]

    // workspace layout. histA shared by both phases; payload region shared:
    // pxs (16 MB, dead after bucket_msg) aliases pc (16 MB, written strictly
    // later in stream order). No memsets needed anywhere.
    const size_t HIST_ELEMS =
        ((size_t)NB_SUB * NBKT_S > (size_t)NB_ALL * NBKT_A)
            ? (size_t)NB_SUB * NBKT_S : (size_t)NB_ALL * NBKT_A;
    char* ws = (char*)d_ws;
    int* histA  = (int*)ws;  ws += ((HIST_ELEMS * 4 + 15) / 16) * 16;
    int* tot_s  = (int*)ws;  ws += ((sizeof(int) * NBKT_S + 15) / 16) * 16;
    int* base_s = (int*)ws;  ws += ((sizeof(int) * NBKT_S + 15) / 16) * 16;
    int* tot_a  = (int*)ws;  ws += ((sizeof(int) * NBKT_A + 15) / 16) * 16;
    int* base_a = (int*)ws;  ws += ((sizeof(int) * NBKT_A + 15) / 16) * 16;
    char* P = ws;                                     // payload union, 16 MB
    float2* pxs = (float2*)P;                         // [E_SUB]  16 MB
    float*  pc  = (float*)P;                          // [E_ALL]  16 MB

    // phase 1: v
    hist_sub_kernel<<<NB_SUB, 1024, 0, stream>>>(rxn_sub, histA);
    scan_cols_kernel<<<NBKT_S, 256, 0, stream>>>(histA, tot_s, NB_SUB, NBKT_S);
    scan_base_kernel<<<1, 256, 0, stream>>>(tot_s, base_s, NBKT_S);
    scatter_bin_sub_kernel<<<NB_SUB, 1024, 0, stream>>>(
        x_met, sto_sub, met_sub, rxn_sub, histA, base_s, pxs);
    bucket_msg_kernel<<<NBKT_S, 1024, 0, stream>>>(
        pxs, base_s, tot_s, W1m, b1m, W2m, b2m, W1r, b1r, W2r, b2r, v);

    // phase 2: dxdt
    hist_all_kernel<<<NB_ALL, 1024, 0, stream>>>(met_all, histA);
    scan_cols_kernel<<<NBKT_A, 256, 0, stream>>>(histA, tot_a, NB_ALL, NBKT_A);
    scan_base_kernel<<<1, 256, 0, stream>>>(tot_a, base_a, NBKT_A);
    scatter_bin_kernel<<<NB_ALL, 1024, 0, stream>>>(
        sto_all, v, met_all, rxn_all, histA, base_a, pc);
    bucket_accum_kernel<<<NBKT_A, 1024, 0, stream>>>(pc, base_a, tot_a, dxdt);
}

// Round 13
// 565.334 us; speedup vs baseline: 1.2441x; 1.0004x over previous
//
#include <hip/hip_runtime.h>

#define N_MET 100000
#define N_RXN 50000
#define E_SUB 2000000
#define E_ALL 4000000
#define MSG_DIM 16
#define HIDDEN 32

// dxdt-side binning: buckets of 256 metabolites, fixed 4096-edge tiles.
#define NBKT_A 391            // ceil(100000/256)
#define NB_ALL 977            // ceil(4000000/4096)
// v-side binning: buckets of 64 reactions, fixed 4096-edge tiles.
#define NBKT_S 782            // ceil(50000/64)
#define NB_SUB 489            // ceil(2000000/4096)

// HW model (R1-R12): scattered GLOBAL atomics = memory-side ~19-20 G ops/s
// wall; LDS atomics exempt. R11: <16 waves/CU starves latency hiding.
// R12: bucket_msg was LDS-READ-THROUGHPUT bound — re-reading 19 wave-uniform
// b32 weights per edge (~19M ds_read instrs). Fix: 4 edges/thread + b128
// weight loads (15x fewer LDS instrs) + exp-based tanh.

__device__ __forceinline__ float fast_tanh(float x) {
    // tanh(x) = sign(x) * (1 - 2/(e^{2|x|}+1)); branch-free, v_exp+v_rcp.
    const float ax = fabsf(x);
    const float e = __expf(2.0f * ax);
    const float t = 1.0f - 2.0f * __builtin_amdgcn_rcpf(e + 1.0f);
    return copysignf(t, x);
}

// ---- generic scans -----------------------------------------------------------

__global__ __launch_bounds__(256) void scan_cols_kernel(
    int* __restrict__ hist, int* __restrict__ tot, int nblocks, int nbkt)
{
    __shared__ int wsum[4];
    const int b = blockIdx.x;
    const int t = threadIdx.x, lane = t & 63, w = t >> 6;
    int carry = 0;
    for (int basei = 0; basei < nblocks; basei += 256) {
        const int bk = basei + t;
        const int val = (bk < nblocks) ? hist[(size_t)bk * nbkt + b] : 0;
        int x = val;
#pragma unroll
        for (int off = 1; off < 64; off <<= 1) {
            const int y = __shfl_up(x, off);
            if (lane >= off) x += y;
        }
        if (lane == 63) wsum[w] = x;
        __syncthreads();
        if (w == 0) {
            int s = (lane < 4) ? wsum[lane] : 0;
#pragma unroll
            for (int off = 1; off < 4; off <<= 1) {
                const int y = __shfl_up(s, off);
                if (lane >= off) s += y;
            }
            if (lane < 4) wsum[lane] = s;
        }
        __syncthreads();
        const int excl = carry + ((w > 0) ? wsum[w - 1] : 0) + x - val;
        if (bk < nblocks) hist[(size_t)bk * nbkt + b] = excl;
        carry += wsum[3];
        __syncthreads();
    }
    if (t == 0) tot[b] = carry;
}

__global__ __launch_bounds__(256) void scan_base_kernel(
    const int* __restrict__ tot, int* __restrict__ base, int nbkt)
{
    __shared__ int wsum[4];
    const int t = threadIdx.x, lane = t & 63, w = t >> 6;
    int carry = 0;
    for (int basei = 0; basei < nbkt; basei += 256) {
        const int i = basei + t;
        const int val = (i < nbkt) ? tot[i] : 0;
        int x = val;
#pragma unroll
        for (int off = 1; off < 64; off <<= 1) {
            const int y = __shfl_up(x, off);
            if (lane >= off) x += y;
        }
        if (lane == 63) wsum[w] = x;
        __syncthreads();
        if (w == 0) {
            int s = (lane < 4) ? wsum[lane] : 0;
#pragma unroll
            for (int off = 1; off < 4; off <<= 1) {
                const int y = __shfl_up(s, off);
                if (lane >= off) s += y;
            }
            if (lane < 4) wsum[lane] = s;
        }
        __syncthreads();
        const int excl = carry + ((w > 0) ? wsum[w - 1] : 0) + x - val;
        if (i < nbkt) base[i] = excl;
        carry += wsum[3];
        __syncthreads();
    }
}

// ---- Phase 1: v via reaction-bucket binning ---------------------------------

__global__ __launch_bounds__(1024) void hist_sub_kernel(
    const int* __restrict__ rxn_sub, int* __restrict__ hist)
{
    __shared__ int hb[NBKT_S];
    const int t = threadIdx.x, bk = blockIdx.x;
    for (int i = t; i < NBKT_S; i += 1024) hb[i] = 0;
    __syncthreads();
    const int i = bk * 1024 + t;
    if (i < E_SUB / 4) {
        const int4 r = ((const int4*)rxn_sub)[i];
        atomicAdd(&hb[r.x >> 6], 1);
        atomicAdd(&hb[r.y >> 6], 1);
        atomicAdd(&hb[r.z >> 6], 1);
        atomicAdd(&hb[r.w >> 6], 1);
    }
    __syncthreads();
    for (int i2 = t; i2 < NBKT_S; i2 += 1024) hist[bk * NBKT_S + i2] = hb[i2];
}

// scatter: LDS-atomic rank into per-(block,bucket) runs; single float2
// payload {x, s'} where s' carries rxn&63 in its low 6 mantissa bits.
__global__ __launch_bounds__(1024) void scatter_bin_sub_kernel(
    const float* __restrict__ x_met, const float* __restrict__ sto_sub,
    const int* __restrict__ met_sub, const int* __restrict__ rxn_sub,
    const int* __restrict__ hist, const int* __restrict__ base,
    float2* __restrict__ pxs)
{
    __shared__ int offs[NBKT_S];
    const int t = threadIdx.x, bk = blockIdx.x;
    for (int i = t; i < NBKT_S; i += 1024)
        offs[i] = hist[bk * NBKT_S + i] + base[i];
    __syncthreads();
#pragma unroll
    for (int it = 0; it < 4; ++it) {
        const int e = bk * 4096 + it * 1024 + t;
        if (e < E_SUB) {
            const int r = rxn_sub[e];
            const float x = x_met[met_sub[e]];
            const int sb = (__float_as_int(sto_sub[e]) & ~63) | (r & 63);
            const int idx = atomicAdd(&offs[r >> 6], 1);
            pxs[idx] = make_float2(x, __int_as_float(sb));
        }
    }
}

// one block (1024 thr) per bucket of 64 reactions. 4 EDGES PER THREAD so each
// LDS weight read is amortized over 4 edges; weights read as b128 (float4).
// j-loop unroll 1: msg[4][16]=64 VGPRs live; (1024,4) = 128-VGPR cap. R5/R6
// lesson: deeper unroll here spills to scratch (GBs of HBM traffic).
__global__ __launch_bounds__(1024, 4) void bucket_msg_kernel(
    const float2* __restrict__ pxs,
    const int* __restrict__ base, const int* __restrict__ tot,
    const float* __restrict__ W1m, const float* __restrict__ b1m,
    const float* __restrict__ W2m, const float* __restrict__ b2m,
    const float* __restrict__ W1r, const float* __restrict__ b1r,
    const float* __restrict__ W2r, const float* __restrict__ b2r,
    float* __restrict__ v)
{
    __shared__ float4 sW1p[HIDDEN];        // {W1[0][j], W1[1][j], b1[j], 0}
    __shared__ float4 sW2m4[HIDDEN * 4];   // row j = 4 float4 (layout == W2m)
    __shared__ float sb2m[MSG_DIM];
    __shared__ float sW1r[MSG_DIM * HIDDEN];
    __shared__ float sb1r[HIDDEN];
    __shared__ float sW2r[HIDDEN];
    __shared__ float sb2r;
    __shared__ float sh[64 * 17];          // h[64 rxns][16+1 pad]
    __shared__ int   scnt[64];
    const int t = threadIdx.x;
    if (t < HIDDEN) sW1p[t] = make_float4(W1m[t], W1m[HIDDEN + t], b1m[t], 0.0f);
    if (t < HIDDEN * MSG_DIM) ((float*)sW2m4)[t] = W2m[t];
    if (t < MSG_DIM)          sb2m[t] = b2m[t];
    if (t < MSG_DIM * HIDDEN) sW1r[t] = W1r[t];
    if (t >= 512 && t < 512 + HIDDEN) { sb1r[t - 512] = b1r[t - 512]; sW2r[t - 512] = W2r[t - 512]; }
    if (t == 600) sb2r = b2r[0];
    for (int i = t; i < 64 * 17; i += 1024) sh[i] = 0.0f;
    if (t < 64) scnt[t] = 0;
    __syncthreads();

    const int b = blockIdx.x;
    const int beg = base[b];
    const int end = beg + tot[b];

    for (int i0 = beg + t; i0 < end; i0 += 4096) {
        const int i1 = i0 + 1024, i2 = i0 + 2048, i3 = i0 + 3072;
        const float2 z2 = make_float2(0.0f, 0.0f);
        const float2 xs0 = pxs[i0];
        const float2 xs1 = (i1 < end) ? pxs[i1] : z2;
        const float2 xs2 = (i2 < end) ? pxs[i2] : z2;
        const float2 xs3 = (i3 < end) ? pxs[i3] : z2;

        float msg0[MSG_DIM], msg1[MSG_DIM], msg2[MSG_DIM], msg3[MSG_DIM];
#pragma unroll
        for (int d = 0; d < MSG_DIM; ++d) {
            msg0[d] = 0.0f; msg1[d] = 0.0f; msg2[d] = 0.0f; msg3[d] = 0.0f;
        }

#pragma unroll 1
        for (int j = 0; j < HIDDEN; ++j) {
            const float4 wp = sW1p[j];
            const float h0 = fast_tanh(fmaf(xs0.x, wp.x, fmaf(xs0.y, wp.y, wp.z)));
            const float h1 = fast_tanh(fmaf(xs1.x, wp.x, fmaf(xs1.y, wp.y, wp.z)));
            const float h2 = fast_tanh(fmaf(xs2.x, wp.x, fmaf(xs2.y, wp.y, wp.z)));
            const float h3 = fast_tanh(fmaf(xs3.x, wp.x, fmaf(xs3.y, wp.y, wp.z)));
#pragma unroll
            for (int k = 0; k < 4; ++k) {
                const float4 w2 = sW2m4[j * 4 + k];
                msg0[4*k+0] = fmaf(h0, w2.x, msg0[4*k+0]);
                msg0[4*k+1] = fmaf(h0, w2.y, msg0[4*k+1]);
                msg0[4*k+2] = fmaf(h0, w2.z, msg0[4*k+2]);
                msg0[4*k+3] = fmaf(h0, w2.w, msg0[4*k+3]);
                msg1[4*k+0] = fmaf(h1, w2.x, msg1[4*k+0]);
                msg1[4*k+1] = fmaf(h1, w2.y, msg1[4*k+1]);
                msg1[4*k+2] = fmaf(h1, w2.z, msg1[4*k+2]);
                msg1[4*k+3] = fmaf(h1, w2.w, msg1[4*k+3]);
                msg2[4*k+0] = fmaf(h2, w2.x, msg2[4*k+0]);
                msg2[4*k+1] = fmaf(h2, w2.y, msg2[4*k+1]);
                msg2[4*k+2] = fmaf(h2, w2.z, msg2[4*k+2]);
                msg2[4*k+3] = fmaf(h2, w2.w, msg2[4*k+3]);
                msg3[4*k+0] = fmaf(h3, w2.x, msg3[4*k+0]);
                msg3[4*k+1] = fmaf(h3, w2.y, msg3[4*k+1]);
                msg3[4*k+2] = fmaf(h3, w2.z, msg3[4*k+2]);
                msg3[4*k+3] = fmaf(h3, w2.w, msg3[4*k+3]);
            }
        }

        {
            const int rl = __float_as_int(xs0.y) & 63;
#pragma unroll
            for (int d = 0; d < MSG_DIM; ++d) atomicAdd(&sh[rl * 17 + d], msg0[d]);
            atomicAdd(&scnt[rl], 1);
        }
        if (i1 < end) {
            const int rl = __float_as_int(xs1.y) & 63;
#pragma unroll
            for (int d = 0; d < MSG_DIM; ++d) atomicAdd(&sh[rl * 17 + d], msg1[d]);
            atomicAdd(&scnt[rl], 1);
        }
        if (i2 < end) {
            const int rl = __float_as_int(xs2.y) & 63;
#pragma unroll
            for (int d = 0; d < MSG_DIM; ++d) atomicAdd(&sh[rl * 17 + d], msg2[d]);
            atomicAdd(&scnt[rl], 1);
        }
        if (i3 < end) {
            const int rl = __float_as_int(xs3.y) & 63;
#pragma unroll
            for (int d = 0; d < MSG_DIM; ++d) atomicAdd(&sh[rl * 17 + d], msg3[d]);
            atomicAdd(&scnt[rl], 1);
        }
    }
    __syncthreads();

    // rate MLP: thread t (<64) owns reaction b*64+t
    if (t < 64) {
        const int r = b * 64 + t;
        if (r < N_RXN) {
            const float cnt = (float)scnt[t];
            float h[MSG_DIM];
#pragma unroll
            for (int d = 0; d < MSG_DIM; ++d)
                h[d] = fmaf(cnt, sb2m[d], sh[t * 17 + d]);
            float acc = sb2r;
#pragma unroll 2
            for (int j = 0; j < HIDDEN; ++j) {
                float z = sb1r[j];
#pragma unroll
                for (int d = 0; d < MSG_DIM; ++d)
                    z = fmaf(h[d], sW1r[d * HIDDEN + j], z);
                acc = fmaf(fast_tanh(z), sW2r[j], acc);
            }
            v[r] = fmaxf(acc, 0.0f) + log1pf(expf(-fabsf(acc)));
        }
    }
}

// ---- Phase 2: dxdt via metabolite-bucket binning ----------------------------

__global__ __launch_bounds__(1024) void hist_all_kernel(
    const int* __restrict__ met_all, int* __restrict__ hist)
{
    __shared__ int hb[NBKT_A];
    const int t = threadIdx.x, bk = blockIdx.x;
    for (int i = t; i < NBKT_A; i += 1024) hb[i] = 0;
    __syncthreads();
    const int i = bk * 1024 + t;
    if (i < E_ALL / 4) {
        const int4 m = ((const int4*)met_all)[i];
        atomicAdd(&hb[m.x >> 8], 1);
        atomicAdd(&hb[m.y >> 8], 1);
        atomicAdd(&hb[m.z >> 8], 1);
        atomicAdd(&hb[m.w >> 8], 1);
    }
    __syncthreads();
    for (int i2 = t; i2 < NBKT_A; i2 += 1024) hist[bk * NBKT_A + i2] = hb[i2];
}

// scatter: single 4B payload — contribution c with met&255 packed into its
// low 8 mantissa bits (rel err ~3e-5; threshold 0.56).
__global__ __launch_bounds__(1024) void scatter_bin_kernel(
    const float* __restrict__ sto_all, const float* __restrict__ v,
    const int* __restrict__ met_all, const int* __restrict__ rxn_all,
    const int* __restrict__ hist, const int* __restrict__ base,
    float* __restrict__ pc)
{
    __shared__ int offs[NBKT_A];
    const int t = threadIdx.x, bk = blockIdx.x;
    for (int i = t; i < NBKT_A; i += 1024)
        offs[i] = hist[bk * NBKT_A + i] + base[i];
    __syncthreads();
#pragma unroll
    for (int it = 0; it < 4; ++it) {
        const int e = bk * 4096 + it * 1024 + t;
        if (e < E_ALL) {
            const int m = met_all[e];
            const float c = sto_all[e] * v[rxn_all[e]];
            const int cb = (__float_as_int(c) & ~255) | (m & 255);
            const int idx = atomicAdd(&offs[m >> 8], 1);
            pc[idx] = __int_as_float(cb);
        }
    }
}

__global__ __launch_bounds__(1024) void bucket_accum_kernel(
    const float* __restrict__ pc,
    const int* __restrict__ base, const int* __restrict__ tot,
    float* __restrict__ dxdt)
{
    __shared__ float acc[256];
    const int b = blockIdx.x, t = threadIdx.x;
    if (t < 256) acc[t] = 0.0f;
    __syncthreads();
    const int beg = base[b];
    const int end = beg + tot[b];
    for (int i = beg + t; i < end; i += 1024) {
        const float pv = pc[i];
        atomicAdd(&acc[__float_as_int(pv) & 255], pv);
    }
    __syncthreads();
    if (t < 256) {
        const int met = b * 256 + t;
        if (met < N_MET) dxdt[met] = acc[t];
    }
}

extern "C" void kernel_launch(void* const* d_in, const int* in_sizes, int n_in,
                              void* d_out, int out_size, void* d_ws, size_t ws_size,
                              hipStream_t stream) {
    const float* x_met   = (const float*)d_in[0];
    const float* sto_sub = (const float*)d_in[1];
    const float* sto_all = (const float*)d_in[2];
    const float* W1m     = (const float*)d_in[3];
    const float* b1m     = (const float*)d_in[4];
    const float* W2m     = (const float*)d_in[5];
    const float* b2m     = (const float*)d_in[6];
    const float* W1r     = (const float*)d_in[7];
    const float* b1r     = (const float*)d_in[8];
    const float* W2r     = (const float*)d_in[9];
    const float* b2r     = (const float*)d_in[10];
    const int*   met_sub = (const int*)d_in[11];
    const int*   rxn_sub = (const int*)d_in[12];
    const int*   met_all = (const int*)d_in[13];
    const int*   rxn_all = (const int*)d_in[14];

    float* dxdt = (float*)d_out;             // [N_MET]
    float* v    = dxdt + N_MET;              // [N_RXN]

    // workspace layout. histA shared by both phases; payload region shared:
    // pxs (16 MB, dead after bucket_msg) aliases pc (16 MB, written strictly
    // later in stream order). No memsets needed anywhere.
    const size_t HIST_ELEMS =
        ((size_t)NB_SUB * NBKT_S > (size_t)NB_ALL * NBKT_A)
            ? (size_t)NB_SUB * NBKT_S : (size_t)NB_ALL * NBKT_A;
    char* ws = (char*)d_ws;
    int* histA  = (int*)ws;  ws += ((HIST_ELEMS * 4 + 15) / 16) * 16;
    int* tot_s  = (int*)ws;  ws += ((sizeof(int) * NBKT_S + 15) / 16) * 16;
    int* base_s = (int*)ws;  ws += ((sizeof(int) * NBKT_S + 15) / 16) * 16;
    int* tot_a  = (int*)ws;  ws += ((sizeof(int) * NBKT_A + 15) / 16) * 16;
    int* base_a = (int*)ws;  ws += ((sizeof(int) * NBKT_A + 15) / 16) * 16;
    char* P = ws;                                     // payload union, 16 MB
    float2* pxs = (float2*)P;                         // [E_SUB]  16 MB
    float*  pc  = (float*)P;                          // [E_ALL]  16 MB

    // phase 1: v
    hist_sub_kernel<<<NB_SUB, 1024, 0, stream>>>(rxn_sub, histA);
    scan_cols_kernel<<<NBKT_S, 256, 0, stream>>>(histA, tot_s, NB_SUB, NBKT_S);
    scan_base_kernel<<<1, 256, 0, stream>>>(tot_s, base_s, NBKT_S);
    scatter_bin_sub_kernel<<<NB_SUB, 1024, 0, stream>>>(
        x_met, sto_sub, met_sub, rxn_sub, histA, base_s, pxs);
    bucket_msg_kernel<<<NBKT_S, 1024, 0, stream>>>(
        pxs, base_s, tot_s, W1m, b1m, W2m, b2m, W1r, b1r, W2r, b2r, v);

    // phase 2: dxdt
    hist_all_kernel<<<NB_ALL, 1024, 0, stream>>>(met_all, histA);
    scan_cols_kernel<<<NBKT_A, 256, 0, stream>>>(histA, tot_a, NB_ALL, NBKT_A);
    scan_base_kernel<<<1, 256, 0, stream>>>(tot_a, base_a, NBKT_A);
    scatter_bin_kernel<<<NB_ALL, 1024, 0, stream>>>(
        sto_all, v, met_all, rxn_all, histA, base_a, pc);
    bucket_accum_kernel<<<NBKT_A, 1024, 0, stream>>>(pc, base_a, tot_a, dxdt);
}